// Round 18
// baseline (309.609 us; speedup 1.0000x reference)
//
#include <hip/hip_runtime.h>
#include <hip/hip_bf16.h>

#define EMBED 768
#define HEADS 12
#define WIN 64
#define DH 64
#define KDIM 768
#define NTILE 12      // KDIM / 64

typedef unsigned short u16;
typedef unsigned int u32;
typedef __attribute__((ext_vector_type(8))) short bf16x8;
typedef __attribute__((ext_vector_type(4))) float f32x4;

__device__ __forceinline__ u16 f2bf(float f) {
  union { float f; u32 u; } x; x.f = f;
  return (u16)((x.u + 0x7fffu + ((x.u >> 16) & 1u)) >> 16);
}

// ---------------- fp32 -> bf16 convert (X) ----------------
__global__ void cvt_f32_bf16(const float* __restrict__ in, u16* __restrict__ out, int n4) {
  int i = blockIdx.x * blockDim.x + threadIdx.x;
  if (i >= n4) return;
  float4 v = ((const float4*)in)[i];
  ushort4 o;
  o.x = f2bf(v.x); o.y = f2bf(v.y); o.z = f2bf(v.z); o.w = f2bf(v.w);
  ((ushort4*)out)[i] = o;
}

// Merged weight prep: QKV per-head interleave + bias perm + Wo cvt.
__global__ void cvt_weights(const float* __restrict__ Wq, const float* __restrict__ Wk,
                            const float* __restrict__ Wv, const float* __restrict__ bq,
                            const float* __restrict__ bk, const float* __restrict__ bv,
                            const float* __restrict__ Wo,
                            u16* __restrict__ Wp, float* __restrict__ bp,
                            u16* __restrict__ Wob) {
  int i = blockIdx.x * 256 + threadIdx.x;        // one float4 each
  const int nqkv = 2304 * 192;
  if (i < nqkv) {
    int r = i / 192, c4 = i % 192;
    int h = r / 192, t = (r % 192) / 64, d = r % 64;
    const float* W = (t == 0) ? Wq : (t == 1) ? Wk : Wv;
    float4 v = *(const float4*)(W + (size_t)(h * 64 + d) * 768 + c4 * 4);
    ushort4 o;
    o.x = f2bf(v.x); o.y = f2bf(v.y); o.z = f2bf(v.z); o.w = f2bf(v.w);
    *(ushort4*)(Wp + (size_t)r * 768 + c4 * 4) = o;
    if (c4 == 0) {
      const float* bb = (t == 0) ? bq : (t == 1) ? bk : bv;
      bp[r] = bb[h * 64 + d];
    }
  } else {
    int j = i - nqkv;                            // 0 .. 768*192-1
    if (j < 768 * 192) {
      float4 v = ((const float4*)Wo)[j];
      ushort4 o;
      o.x = f2bf(v.x); o.y = f2bf(v.y); o.z = f2bf(v.z); o.w = f2bf(v.w);
      ((ushort4*)Wob)[j] = o;
    }
  }
}

// ---------------- Fused QKV-projection + window attention ----------------
// Block = 128 rows (2 windows) x 192 cols, 512 thr = 8 waves (2M x 4N).
// A: LDS dbuf (2x16KB DMA). B: DIRECT global->register, reg-double-buffered
// (L2-resident weight panel; removes 24KB/tile DMA + 48 ds_reads/tile ->
// LDS pipe load ~halved). LDS 54KB -> 2 blocks/CU. Rowblock-grouped XCD map.
__global__ __launch_bounds__(512, 4)
void qkva(const u16* __restrict__ A, const u16* __restrict__ Bw,
          const float* __restrict__ biasp, u16* __restrict__ O) {
  __shared__ char sc_[55296];                    // A 2x16K @0; attn 54K @0 (union)
  const int tid = threadIdx.x;
  const int lane = tid & 63;
  const int wid = tid >> 6;                      // 0..7
  const int wr = wid >> 2, wc = wid & 3;
  const int l15 = lane & 15;

  const int x = blockIdx.x & 7;
  const int k = blockIdx.x >> 3;                 // 0..383
  const int rb = x + ((k / HEADS) << 3);         // rowblock 0..255
  const int head = k % HEADS;
  const int brow = rb << 7;
  const int bcolw = head * 192;

  const int srow = tid >> 3;                     // 0..63
  const int scol = ((tid & 7) ^ (srow & 7)) << 3;   // T2 pre-swizzled source (A only)
  const u16* Asrc = A + (size_t)(brow + srow) * KDIM + scol;

  auto STAGE_A = [&](int b, int u, int kt) {
    __builtin_amdgcn_global_load_lds(
        (const __attribute__((address_space(1))) void*)(Asrc + (size_t)(u << 6) * KDIM + kt),
        (__attribute__((address_space(3))) void*)(sc_ + b * 16384 + (u << 13) + tid * 16), 16, 0, 0);
  };

  const int swz = (l15 & 7) << 4;
  const int cb0 = ((lane >> 4) << 4) ^ swz;
  const int cb1 = (((lane >> 4) + 4) << 4) ^ swz;
  auto pA = [&](int b, int mi) -> const char* {
    return sc_ + b * 16384 + ((wr << 6) + (mi << 4) + l15) * 128;
  };

  // B direct from global: wave's rows [wc*48, +48); frag [nj][kk]:
  // lane l -> row nj*16+(l&15), elems k = kt + (l>>4)*8 + kk*32
  const u16* Bbase = Bw + (size_t)(bcolw + wc * 48 + l15) * KDIM + ((lane >> 4) << 3);
  auto LDB = [&](bf16x8 (*RB)[2], int kt) {
#pragma unroll
    for (int nj = 0; nj < 3; ++nj)
#pragma unroll
      for (int kk = 0; kk < 2; ++kk)
        RB[nj][kk] = *(const bf16x8*)(Bbase + (size_t)(nj << 4) * KDIM + kt + (kk << 5));
  };

  f32x4 acc[4][3];
#pragma unroll
  for (int m = 0; m < 4; ++m)
#pragma unroll
    for (int n = 0; n < 3; ++n) acc[m][n] = (f32x4){0.f, 0.f, 0.f, 0.f};

  bf16x8 RB[2][3][2];

  // prologue: stage A tile 0 (LDS) + load B tile 0 (regs)
#pragma unroll
  for (int u = 0; u < 2; ++u) STAGE_A(0, u, 0);
  LDB(RB[0], 0);
  __syncthreads();

#pragma unroll 2
  for (int t = 0; t < NTILE; ++t) {
    const int b = t & 1;
    if (t + 1 < NTILE) {
      const int kn = (t + 1) << 6;
#pragma unroll
      for (int u = 0; u < 2; ++u) STAGE_A(b ^ 1, u, kn);   // A t+1 lands under MFMA
      LDB(RB[b ^ 1], kn);                                  // B t+1 in flight across tile
    }
#pragma unroll
    for (int mi = 0; mi < 4; ++mi) {
      bf16x8 ra0 = *(const bf16x8*)(pA(b, mi) + cb0);
      bf16x8 ra1 = *(const bf16x8*)(pA(b, mi) + cb1);
#pragma unroll
      for (int nj = 0; nj < 3; ++nj) {
        acc[mi][nj] = __builtin_amdgcn_mfma_f32_16x16x32_bf16(ra0, RB[b][nj][0], acc[mi][nj], 0, 0, 0);
        acc[mi][nj] = __builtin_amdgcn_mfma_f32_16x16x32_bf16(ra1, RB[b][nj][1], acc[mi][nj], 0, 0, 0);
      }
    }
    __syncthreads();                             // A reads done; other block covers drain
  }

  // ---- epilogue: scatter Q,K (row-major) and V (transposed) into attn LDS ----
  u16* qp  = (u16*)sc_;                          // [2][64][72]  Q, later P
  u16* kk_ = (u16*)(sc_ + 18432);                // [2][64][72]  K, later O
  u16* vv  = (u16*)(sc_ + 36864);                // [2][64][72]  V^T (d-major)
#pragma unroll
  for (int mi = 0; mi < 4; ++mi) {
    const int row0 = (wr << 6) + (mi << 4) + ((lane >> 4) << 2);
#pragma unroll
    for (int nj = 0; nj < 3; ++nj) {
      const int col = wc * 48 + (nj << 4) + l15;
      const float bb = biasp[bcolw + col];
#pragma unroll
      for (int rr = 0; rr < 4; ++rr) {
        const int rw = row0 + rr;
        const int win = rw >> 6, rloc = rw & 63;
        const u16 val = f2bf(acc[mi][nj][rr] + bb);
        if (col < 64)       qp [win * 4608 + rloc * 72 + col] = val;
        else if (col < 128) kk_[win * 4608 + rloc * 72 + (col - 64)] = val;
        else                vv [win * 4608 + (col - 128) * 72 + rloc] = val;
      }
    }
  }
  __syncthreads();

  // ---- attention: 4 waves per window; this wave owns rows [qt*16, +16) ----
  const int w = wid >> 2, qt = wid & 3;
  u16* qw = qp + w * 4608;
  u16* kw = kk_ + w * 4608;
  u16* vw = vv + w * 4608;
  const int g8 = (lane >> 4) << 3;
  const int g4 = (lane >> 4) << 2;
  const int rown = qt * 16 + l15;

  f32x4 sacc[4];
#pragma unroll
  for (int t = 0; t < 4; ++t) sacc[t] = (f32x4){0.f, 0.f, 0.f, 0.f};
  bf16x8 aq0 = *(const bf16x8*)(qw + rown * 72 + g8);
  bf16x8 aq1 = *(const bf16x8*)(qw + rown * 72 + 32 + g8);
#pragma unroll
  for (int t = 0; t < 4; ++t) {
    const int kr = t * 16 + l15;
    bf16x8 bk0 = *(const bf16x8*)(kw + kr * 72 + g8);
    bf16x8 bk1 = *(const bf16x8*)(kw + kr * 72 + 32 + g8);
    sacc[t] = __builtin_amdgcn_mfma_f32_16x16x32_bf16(aq0, bk0, sacc[t], 0, 0, 0);
    sacc[t] = __builtin_amdgcn_mfma_f32_16x16x32_bf16(aq1, bk1, sacc[t], 0, 0, 0);
  }
#pragma unroll
  for (int t = 0; t < 4; ++t)
#pragma unroll
    for (int r = 0; r < 4; ++r) sacc[t][r] *= 0.125f;

#pragma unroll
  for (int r = 0; r < 4; ++r) {
    float m0 = fmaxf(fmaxf(sacc[0][r], sacc[1][r]), fmaxf(sacc[2][r], sacc[3][r]));
#pragma unroll
    for (int msk = 1; msk < 16; msk <<= 1) m0 = fmaxf(m0, __shfl_xor(m0, msk));
    float s0 = 0.f;
#pragma unroll
    for (int t = 0; t < 4; ++t) {
      float e = __expf(sacc[t][r] - m0);
      sacc[t][r] = e;
      s0 += e;
    }
#pragma unroll
    for (int msk = 1; msk < 16; msk <<= 1) s0 += __shfl_xor(s0, msk);
    const float inv = 1.f / s0;
#pragma unroll
    for (int t = 0; t < 4; ++t) sacc[t][r] *= inv;
  }

  // P -> qw (Q dead; each wave writes only its own 16 rows)
#pragma unroll
  for (int t = 0; t < 4; ++t)
#pragma unroll
    for (int r = 0; r < 4; ++r)
      qw[(qt * 16 + g4 + r) * 72 + t * 16 + l15] = f2bf(sacc[t][r]);

  // PV
  f32x4 oacc[4];
#pragma unroll
  for (int t = 0; t < 4; ++t) oacc[t] = (f32x4){0.f, 0.f, 0.f, 0.f};
  bf16x8 ap0 = *(const bf16x8*)(qw + rown * 72 + g8);
  bf16x8 ap1 = *(const bf16x8*)(qw + rown * 72 + 32 + g8);
#pragma unroll
  for (int t = 0; t < 4; ++t) {
    const int dr = t * 16 + l15;
    bf16x8 bv0 = *(const bf16x8*)(vw + dr * 72 + g8);
    bf16x8 bv1 = *(const bf16x8*)(vw + dr * 72 + 32 + g8);
    oacc[t] = __builtin_amdgcn_mfma_f32_16x16x32_bf16(ap0, bv0, oacc[t], 0, 0, 0);
    oacc[t] = __builtin_amdgcn_mfma_f32_16x16x32_bf16(ap1, bv1, oacc[t], 0, 0, 0);
  }
  __syncthreads();                               // all QK^T reads of kw done
#pragma unroll
  for (int t = 0; t < 4; ++t)
#pragma unroll
    for (int r = 0; r < 4; ++r)
      kw[(qt * 16 + g4 + r) * 72 + t * 16 + l15] = f2bf(oacc[t][r]);
  __syncthreads();

  // coalesced O store: 128 rows x 128B (2 iters x 8KB)
#pragma unroll
  for (int it = 0; it < 2; ++it) {
    const int f = (it << 9) + tid;
    const int row = f >> 3, c8 = f & 7;
    uint4 v = *(const uint4*)(kk_ + (row >> 6) * 4608 + (row & 63) * 72 + (c8 << 3));
    *(uint4*)(O + (size_t)(brow + row) * 768 + head * 64 + (c8 << 3)) = v;
  }
}

// ---------------- 128x128 NT GEMM (Wo), single-buffer, 4 blocks/CU ----------------
__global__ __launch_bounds__(256, 4)
void gemm128(const u16* __restrict__ A, const u16* __restrict__ Bw,
             const float* __restrict__ bias, float* __restrict__ dF, int N) {
  __shared__ char sc_[32768];                    // A 16K @0; B 16K @16384 (single buf)
  const int tid = threadIdx.x;
  const int lane = tid & 63;
  const int wid = tid >> 6;
  const int wr = wid >> 1, wc = wid & 1;
  const int l15 = lane & 15;

  // grid 1536 = 8 x 192; rowpanel-grouped per XCD
  const int x = blockIdx.x & 7;
  const int k = blockIdx.x >> 3;                 // 0..191
  const int rbp = x + ((k / 6) << 3);            // row-panel 0..255
  const int cbp = k % 6;
  const int brow = rbp << 7;
  const int bcol = cbp << 7;

  const int srow = tid >> 3;
  const int scol = ((tid & 7) ^ (srow & 7)) << 3;
  const u16* Asrc = A + (size_t)(brow + srow) * KDIM + scol;
  const u16* Bsrc = Bw + (size_t)(bcol + srow) * KDIM + scol;
  const int lds_woff = wid << 10;

  auto STAGE_A = [&](int u, int kt) {
    __builtin_amdgcn_global_load_lds(
        (const __attribute__((address_space(1))) void*)(Asrc + (size_t)(u << 5) * KDIM + kt),
        (__attribute__((address_space(3))) void*)(sc_ + (u << 12) + lds_woff), 16, 0, 0);
  };
  auto STAGE_B = [&](int u, int kt) {
    __builtin_amdgcn_global_load_lds(
        (const __attribute__((address_space(1))) void*)(Bsrc + (size_t)(u << 5) * KDIM + kt),
        (__attribute__((address_space(3))) void*)(sc_ + 16384 + (u << 12) + lds_woff), 16, 0, 0);
  };

  const int swz = (l15 & 7) << 4;
  const int cb0 = ((lane >> 4) << 4) ^ swz;
  const int cb1 = (((lane >> 4) + 4) << 4) ^ swz;
  auto pA = [&](int mi) -> const char* {
    return sc_ + (((wr << 6) + (mi << 4) + l15)) * 128;
  };
  auto pB = [&](int nj) -> const char* {
    return sc_ + 16384 + (((wc << 6) + (nj << 4) + l15)) * 128;
  };

  f32x4 acc[4][4];
#pragma unroll
  for (int m = 0; m < 4; ++m)
#pragma unroll
    for (int n = 0; n < 4; ++n) acc[m][n] = (f32x4){0.f, 0.f, 0.f, 0.f};

  for (int t = 0; t < NTILE; ++t) {
    const int kt = t << 6;
#pragma unroll
    for (int u = 0; u < 4; ++u) STAGE_A(u, kt);
#pragma unroll
    for (int u = 0; u < 4; ++u) STAGE_B(u, kt);
    __syncthreads();                             // stage landed
    bf16x8 rb[4][2];
#pragma unroll
    for (int nj = 0; nj < 4; ++nj) {
      rb[nj][0] = *(const bf16x8*)(pB(nj) + cb0);
      rb[nj][1] = *(const bf16x8*)(pB(nj) + cb1);
    }
#pragma unroll
    for (int q = 0; q < 4; ++q) {
      bf16x8 ra0 = *(const bf16x8*)(pA(q) + cb0);
      bf16x8 ra1 = *(const bf16x8*)(pA(q) + cb1);
#pragma unroll
      for (int nj = 0; nj < 4; ++nj) {
        acc[q][nj] = __builtin_amdgcn_mfma_f32_16x16x32_bf16(ra0, rb[nj][0], acc[q][nj], 0, 0, 0);
        acc[q][nj] = __builtin_amdgcn_mfma_f32_16x16x32_bf16(ra1, rb[nj][1], acc[q][nj], 0, 0, 0);
      }
    }
    __syncthreads();                             // all reads done before re-stage
  }

  // f32 epilogue: two col-half passes via 32KB LDS (128x64 f32)
  float* smf = (float*)sc_;
#pragma unroll
  for (int p = 0; p < 2; ++p) {
    if (p) __syncthreads();
    if (wc == p) {
#pragma unroll
      for (int mi = 0; mi < 4; ++mi)
#pragma unroll
        for (int nj = 0; nj < 4; ++nj) {
          const int col = (nj << 4) + l15;
          const float bb = bias[bcol + (p << 6) + col];
          const int row0 = (wr << 6) + (mi << 4) + ((lane >> 4) << 2);
#pragma unroll
          for (int rr = 0; rr < 4; ++rr)
            smf[(row0 + rr) << 6 | col] = acc[mi][nj][rr] + bb;
        }
    }
    __syncthreads();
#pragma unroll
    for (int it = 0; it < 8; ++it) {
      const int f = (it << 8) + tid;
      const int row = f >> 4, c4 = f & 15;
      float4 v = *(const float4*)(smf + (row << 6) + (c4 << 2));
      *(float4*)(dF + (size_t)(brow + row) * N + bcol + (p << 6) + (c4 << 2)) = v;
    }
  }
}

extern "C" void kernel_launch(void* const* d_in, const int* in_sizes, int n_in,
                              void* d_out, int out_size, void* d_ws, size_t ws_size,
                              hipStream_t stream) {
  const float* q  = (const float*)d_in[0];
  const float* Wq = (const float*)d_in[3];
  const float* bq = (const float*)d_in[4];
  const float* Wk = (const float*)d_in[5];
  const float* bk = (const float*)d_in[6];
  const float* Wv = (const float*)d_in[7];
  const float* bv = (const float*)d_in[8];
  const float* Wo = (const float*)d_in[9];
  const float* bo = (const float*)d_in[10];

  const int C = EMBED;
  const int M = in_sizes[0] / C;                 // 32768
  const size_t xsz = (size_t)M * C;
  const size_t wsz = (size_t)C * C;

  u16* Xb = (u16*)d_out;                         // scratch (overwritten by Wo GEMM)
  u16* Ob = (u16*)d_ws;                          // attention output, bf16 [M][768]
  u16* Wp = Ob + xsz;                            // per-head QKV weights [2304][768]
  u16* Wob = Wp + 3 * wsz;
  float* biasp = (float*)(Wob + wsz);            // 2304 f32 permuted bias

  {
    int n4 = (int)(xsz >> 2);
    cvt_f32_bf16<<<(n4 + 255) / 256, 256, 0, stream>>>(q, Xb, n4);
    const int nitems = 2304 * 192 + 768 * 192;   // QKV-perm + Wo, one launch
    cvt_weights<<<(nitems + 255) / 256, 256, 0, stream>>>(
        Wq, Wk, Wv, bq, bk, bv, Wo, Wp, biasp, Wob);
  }

  // Fused QKV projection + attention: 3072 blocks (rowblock-grouped per XCD)
  qkva<<<(M / 128) * HEADS, 512, 0, stream>>>(Xb, Wp, biasp, Ob);

  // Output projection: 1536 blocks (rowpanel-grouped per XCD, 4 blocks/CU)
  gemm128<<<(M / 128) * (C / 128), 256, 0, stream>>>(Ob, Wob, bo, (float*)d_out, C);
}

// Round 19
// 214.002 us; speedup vs baseline: 1.4468x; 1.4468x over previous
//
#include <hip/hip_runtime.h>
#include <hip/hip_bf16.h>

#define EMBED 768
#define HEADS 12
#define WIN 64
#define DH 64
#define KDIM 768
#define NTILE 12      // KDIM / 64

typedef unsigned short u16;
typedef unsigned int u32;
typedef __attribute__((ext_vector_type(8))) short bf16x8;
typedef __attribute__((ext_vector_type(4))) float f32x4;

__device__ __forceinline__ u16 f2bf(float f) {
  union { float f; u32 u; } x; x.f = f;
  return (u16)((x.u + 0x7fffu + ((x.u >> 16) & 1u)) >> 16);
}

// ---------------- fp32 -> bf16 convert (X) ----------------
__global__ void cvt_f32_bf16(const float* __restrict__ in, u16* __restrict__ out, int n4) {
  int i = blockIdx.x * blockDim.x + threadIdx.x;
  if (i >= n4) return;
  float4 v = ((const float4*)in)[i];
  ushort4 o;
  o.x = f2bf(v.x); o.y = f2bf(v.y); o.z = f2bf(v.z); o.w = f2bf(v.w);
  ((ushort4*)out)[i] = o;
}

// Merged weight prep: items [0, 2304*192) -> per-head-interleaved QKV weights
// (row r = h*192 + {Wq|Wk|Wv}[h*64+d]) + permuted bias; items beyond -> Wo cvt.
__global__ void cvt_weights(const float* __restrict__ Wq, const float* __restrict__ Wk,
                            const float* __restrict__ Wv, const float* __restrict__ bq,
                            const float* __restrict__ bk, const float* __restrict__ bv,
                            const float* __restrict__ Wo,
                            u16* __restrict__ Wp, float* __restrict__ bp,
                            u16* __restrict__ Wob) {
  int i = blockIdx.x * 256 + threadIdx.x;        // one float4 each
  const int nqkv = 2304 * 192;
  if (i < nqkv) {
    int r = i / 192, c4 = i % 192;
    int h = r / 192, t = (r % 192) / 64, d = r % 64;
    const float* W = (t == 0) ? Wq : (t == 1) ? Wk : Wv;
    float4 v = *(const float4*)(W + (size_t)(h * 64 + d) * 768 + c4 * 4);
    ushort4 o;
    o.x = f2bf(v.x); o.y = f2bf(v.y); o.z = f2bf(v.z); o.w = f2bf(v.w);
    *(ushort4*)(Wp + (size_t)r * 768 + c4 * 4) = o;
    if (c4 == 0) {
      const float* bb = (t == 0) ? bq : (t == 1) ? bk : bv;
      bp[r] = bb[h * 64 + d];
    }
  } else {
    int j = i - nqkv;                            // 0 .. 768*192-1
    if (j < 768 * 192) {
      float4 v = ((const float4*)Wo)[j];
      ushort4 o;
      o.x = f2bf(v.x); o.y = f2bf(v.y); o.z = f2bf(v.z); o.w = f2bf(v.w);
      ((ushort4*)Wob)[j] = o;
    }
  }
}

// ---------------- Fused QKV-projection + window attention (best config) ----------------
// Block = 128 rows (2 windows) x 192 cols, 512 thr = 8 waves (2M x 4N).
// LDS 80KB dbuf (A 2x16K, B 2x24K via global_load_lds DMA) -> 2 blocks/CU =
// 4 waves/SIMD, VGPR ~60 (no tight cap -> no spill). Rowblock-grouped XCD map.
__global__ __launch_bounds__(512, 4)
void qkva(const u16* __restrict__ A, const u16* __restrict__ Bw,
          const float* __restrict__ biasp, u16* __restrict__ O) {
  __shared__ char sc_[81920];                    // A 2x16K @0; B 2x24K @32768; attn 54K
  const int tid = threadIdx.x;
  const int lane = tid & 63;
  const int wid = tid >> 6;                      // 0..7
  const int wr = wid >> 2, wc = wid & 3;
  const int l15 = lane & 15;

  const int x = blockIdx.x & 7;
  const int k = blockIdx.x >> 3;                 // 0..383
  const int rb = x + ((k / HEADS) << 3);         // rowblock 0..255
  const int head = k % HEADS;
  const int brow = rb << 7;
  const int bcolw = head * 192;

  const int srow = tid >> 3;                     // 0..63
  const int scol = ((tid & 7) ^ (srow & 7)) << 3;   // T2 pre-swizzled source
  const u16* Asrc = A + (size_t)(brow + srow) * KDIM + scol;
  const u16* Bsrc = Bw + (size_t)(bcolw + srow) * KDIM + scol;

  auto STAGE_A = [&](int b, int u, int kt) {
    __builtin_amdgcn_global_load_lds(
        (const __attribute__((address_space(1))) void*)(Asrc + (size_t)(u << 6) * KDIM + kt),
        (__attribute__((address_space(3))) void*)(sc_ + b * 16384 + (u << 13) + tid * 16), 16, 0, 0);
  };
  auto STAGE_B = [&](int b, int u, int kt) {
    __builtin_amdgcn_global_load_lds(
        (const __attribute__((address_space(1))) void*)(Bsrc + (size_t)(u << 6) * KDIM + kt),
        (__attribute__((address_space(3))) void*)(sc_ + 32768 + b * 24576 + (u << 13) + tid * 16), 16, 0, 0);
  };

  const int swz = (l15 & 7) << 4;
  const int cb0 = ((lane >> 4) << 4) ^ swz;
  const int cb1 = (((lane >> 4) + 4) << 4) ^ swz;
  auto pA = [&](int b, int mi) -> const char* {
    return sc_ + b * 16384 + ((wr << 6) + (mi << 4) + l15) * 128;
  };
  auto pB = [&](int b, int nj) -> const char* {
    return sc_ + 32768 + b * 24576 + (wc * 48 + (nj << 4) + l15) * 128;
  };

  f32x4 acc[4][3];
#pragma unroll
  for (int m = 0; m < 4; ++m)
#pragma unroll
    for (int n = 0; n < 3; ++n) acc[m][n] = (f32x4){0.f, 0.f, 0.f, 0.f};

#pragma unroll
  for (int u = 0; u < 2; ++u) STAGE_A(0, u, 0);
#pragma unroll
  for (int u = 0; u < 3; ++u) STAGE_B(0, u, 0);
  __syncthreads();

  for (int t = 0; t < NTILE; ++t) {
    const int b = t & 1;
    if (t + 1 < NTILE) {                         // next-tile stage lands under MFMA
      const int kn = (t + 1) << 6;
#pragma unroll
      for (int u = 0; u < 2; ++u) STAGE_A(b ^ 1, u, kn);
#pragma unroll
      for (int u = 0; u < 3; ++u) STAGE_B(b ^ 1, u, kn);
    }
    bf16x8 rb_[3][2];
#pragma unroll
    for (int nj = 0; nj < 3; ++nj) {
      rb_[nj][0] = *(const bf16x8*)(pB(b, nj) + cb0);
      rb_[nj][1] = *(const bf16x8*)(pB(b, nj) + cb1);
    }
#pragma unroll
    for (int mi = 0; mi < 4; ++mi) {
      bf16x8 ra0 = *(const bf16x8*)(pA(b, mi) + cb0);
      bf16x8 ra1 = *(const bf16x8*)(pA(b, mi) + cb1);
#pragma unroll
      for (int nj = 0; nj < 3; ++nj) {
        acc[mi][nj] = __builtin_amdgcn_mfma_f32_16x16x32_bf16(ra0, rb_[nj][0], acc[mi][nj], 0, 0, 0);
        acc[mi][nj] = __builtin_amdgcn_mfma_f32_16x16x32_bf16(ra1, rb_[nj][1], acc[mi][nj], 0, 0, 0);
      }
    }
    __syncthreads();
  }

  // ---- epilogue: scatter Q,K (row-major) and V (transposed) into attn LDS ----
  u16* qp  = (u16*)sc_;                          // [2][64][72]  Q, later P
  u16* kk_ = (u16*)(sc_ + 18432);                // [2][64][72]  K, later O
  u16* vv  = (u16*)(sc_ + 36864);                // [2][64][72]  V^T (d-major)
#pragma unroll
  for (int mi = 0; mi < 4; ++mi) {
    const int row0 = (wr << 6) + (mi << 4) + ((lane >> 4) << 2);
#pragma unroll
    for (int nj = 0; nj < 3; ++nj) {
      const int col = wc * 48 + (nj << 4) + l15;
      const float bb = biasp[bcolw + col];
#pragma unroll
      for (int rr = 0; rr < 4; ++rr) {
        const int rw = row0 + rr;
        const int win = rw >> 6, rloc = rw & 63;
        const u16 val = f2bf(acc[mi][nj][rr] + bb);
        if (col < 64)       qp [win * 4608 + rloc * 72 + col] = val;
        else if (col < 128) kk_[win * 4608 + rloc * 72 + (col - 64)] = val;
        else                vv [win * 4608 + (col - 128) * 72 + rloc] = val;
      }
    }
  }
  __syncthreads();

  // ---- attention: 4 waves per window; this wave owns rows [qt*16, +16) ----
  const int w = wid >> 2, qt = wid & 3;
  u16* qw = qp + w * 4608;
  u16* kw = kk_ + w * 4608;
  u16* vw = vv + w * 4608;
  const int g8 = (lane >> 4) << 3;
  const int g4 = (lane >> 4) << 2;
  const int rown = qt * 16 + l15;

  f32x4 sacc[4];
#pragma unroll
  for (int t = 0; t < 4; ++t) sacc[t] = (f32x4){0.f, 0.f, 0.f, 0.f};
  bf16x8 aq0 = *(const bf16x8*)(qw + rown * 72 + g8);
  bf16x8 aq1 = *(const bf16x8*)(qw + rown * 72 + 32 + g8);
#pragma unroll
  for (int t = 0; t < 4; ++t) {
    const int kr = t * 16 + l15;
    bf16x8 bk0 = *(const bf16x8*)(kw + kr * 72 + g8);
    bf16x8 bk1 = *(const bf16x8*)(kw + kr * 72 + 32 + g8);
    sacc[t] = __builtin_amdgcn_mfma_f32_16x16x32_bf16(aq0, bk0, sacc[t], 0, 0, 0);
    sacc[t] = __builtin_amdgcn_mfma_f32_16x16x32_bf16(aq1, bk1, sacc[t], 0, 0, 0);
  }
#pragma unroll
  for (int t = 0; t < 4; ++t)
#pragma unroll
    for (int r = 0; r < 4; ++r) sacc[t][r] *= 0.125f;

#pragma unroll
  for (int r = 0; r < 4; ++r) {
    float m0 = fmaxf(fmaxf(sacc[0][r], sacc[1][r]), fmaxf(sacc[2][r], sacc[3][r]));
#pragma unroll
    for (int msk = 1; msk < 16; msk <<= 1) m0 = fmaxf(m0, __shfl_xor(m0, msk));
    float s0 = 0.f;
#pragma unroll
    for (int t = 0; t < 4; ++t) {
      float e = __expf(sacc[t][r] - m0);
      sacc[t][r] = e;
      s0 += e;
    }
#pragma unroll
    for (int msk = 1; msk < 16; msk <<= 1) s0 += __shfl_xor(s0, msk);
    const float inv = 1.f / s0;
#pragma unroll
    for (int t = 0; t < 4; ++t) sacc[t][r] *= inv;
  }

  // P -> qw (Q dead; each wave writes only its own 16 rows)
#pragma unroll
  for (int t = 0; t < 4; ++t)
#pragma unroll
    for (int r = 0; r < 4; ++r)
      qw[(qt * 16 + g4 + r) * 72 + t * 16 + l15] = f2bf(sacc[t][r]);

  // PV
  f32x4 oacc[4];
#pragma unroll
  for (int t = 0; t < 4; ++t) oacc[t] = (f32x4){0.f, 0.f, 0.f, 0.f};
  bf16x8 ap0 = *(const bf16x8*)(qw + rown * 72 + g8);
  bf16x8 ap1 = *(const bf16x8*)(qw + rown * 72 + 32 + g8);
#pragma unroll
  for (int t = 0; t < 4; ++t) {
    const int dr = t * 16 + l15;
    bf16x8 bv0 = *(const bf16x8*)(vw + dr * 72 + g8);
    bf16x8 bv1 = *(const bf16x8*)(vw + dr * 72 + 32 + g8);
    oacc[t] = __builtin_amdgcn_mfma_f32_16x16x32_bf16(ap0, bv0, oacc[t], 0, 0, 0);
    oacc[t] = __builtin_amdgcn_mfma_f32_16x16x32_bf16(ap1, bv1, oacc[t], 0, 0, 0);
  }
  __syncthreads();                               // all QK^T reads of kw done
#pragma unroll
  for (int t = 0; t < 4; ++t)
#pragma unroll
    for (int r = 0; r < 4; ++r)
      kw[(qt * 16 + g4 + r) * 72 + t * 16 + l15] = f2bf(oacc[t][r]);
  __syncthreads();

  // coalesced O store: 128 rows x 128B (2 iters x 8KB)
#pragma unroll
  for (int it = 0; it < 2; ++it) {
    const int f = (it << 9) + tid;
    const int row = f >> 3, c8 = f & 7;
    uint4 v = *(const uint4*)(kk_ + (row >> 6) * 4608 + (row & 63) * 72 + (c8 << 3));
    *(uint4*)(O + (size_t)(brow + row) * 768 + head * 64 + (c8 << 3)) = v;
  }
}

// ---------------- 128x128 NT GEMM (Wo), single-buffer, 4 blocks/CU ----------------
__global__ __launch_bounds__(256, 4)
void gemm128(const u16* __restrict__ A, const u16* __restrict__ Bw,
             const float* __restrict__ bias, float* __restrict__ dF, int N) {
  __shared__ char sc_[32768];                    // A 16K @0; B 16K @16384 (single buf)
  const int tid = threadIdx.x;
  const int lane = tid & 63;
  const int wid = tid >> 6;
  const int wr = wid >> 1, wc = wid & 1;
  const int l15 = lane & 15;

  // grid 1536 = 8 x 192; rowpanel-grouped per XCD
  const int x = blockIdx.x & 7;
  const int k = blockIdx.x >> 3;                 // 0..191
  const int rbp = x + ((k / 6) << 3);            // row-panel 0..255
  const int cbp = k % 6;
  const int brow = rbp << 7;
  const int bcol = cbp << 7;

  const int srow = tid >> 3;
  const int scol = ((tid & 7) ^ (srow & 7)) << 3;
  const u16* Asrc = A + (size_t)(brow + srow) * KDIM + scol;
  const u16* Bsrc = Bw + (size_t)(bcol + srow) * KDIM + scol;
  const int lds_woff = wid << 10;

  auto STAGE_A = [&](int u, int kt) {
    __builtin_amdgcn_global_load_lds(
        (const __attribute__((address_space(1))) void*)(Asrc + (size_t)(u << 5) * KDIM + kt),
        (__attribute__((address_space(3))) void*)(sc_ + (u << 12) + lds_woff), 16, 0, 0);
  };
  auto STAGE_B = [&](int u, int kt) {
    __builtin_amdgcn_global_load_lds(
        (const __attribute__((address_space(1))) void*)(Bsrc + (size_t)(u << 5) * KDIM + kt),
        (__attribute__((address_space(3))) void*)(sc_ + 16384 + (u << 12) + lds_woff), 16, 0, 0);
  };

  const int swz = (l15 & 7) << 4;
  const int cb0 = ((lane >> 4) << 4) ^ swz;
  const int cb1 = (((lane >> 4) + 4) << 4) ^ swz;
  auto pA = [&](int mi) -> const char* {
    return sc_ + (((wr << 6) + (mi << 4) + l15)) * 128;
  };
  auto pB = [&](int nj) -> const char* {
    return sc_ + 16384 + (((wc << 6) + (nj << 4) + l15)) * 128;
  };

  f32x4 acc[4][4];
#pragma unroll
  for (int m = 0; m < 4; ++m)
#pragma unroll
    for (int n = 0; n < 4; ++n) acc[m][n] = (f32x4){0.f, 0.f, 0.f, 0.f};

  for (int t = 0; t < NTILE; ++t) {
    const int kt = t << 6;
#pragma unroll
    for (int u = 0; u < 4; ++u) STAGE_A(u, kt);
#pragma unroll
    for (int u = 0; u < 4; ++u) STAGE_B(u, kt);
    __syncthreads();                             // stage landed
    bf16x8 rb[4][2];
#pragma unroll
    for (int nj = 0; nj < 4; ++nj) {
      rb[nj][0] = *(const bf16x8*)(pB(nj) + cb0);
      rb[nj][1] = *(const bf16x8*)(pB(nj) + cb1);
    }
#pragma unroll
    for (int q = 0; q < 4; ++q) {
      bf16x8 ra0 = *(const bf16x8*)(pA(q) + cb0);
      bf16x8 ra1 = *(const bf16x8*)(pA(q) + cb1);
#pragma unroll
      for (int nj = 0; nj < 4; ++nj) {
        acc[q][nj] = __builtin_amdgcn_mfma_f32_16x16x32_bf16(ra0, rb[nj][0], acc[q][nj], 0, 0, 0);
        acc[q][nj] = __builtin_amdgcn_mfma_f32_16x16x32_bf16(ra1, rb[nj][1], acc[q][nj], 0, 0, 0);
      }
    }
    __syncthreads();                             // all reads done before re-stage
  }

  // f32 epilogue: two col-half passes via 32KB LDS (128x64 f32)
  float* smf = (float*)sc_;
#pragma unroll
  for (int p = 0; p < 2; ++p) {
    if (p) __syncthreads();
    if (wc == p) {
#pragma unroll
      for (int mi = 0; mi < 4; ++mi)
#pragma unroll
        for (int nj = 0; nj < 4; ++nj) {
          const int col = (nj << 4) + l15;
          const float bb = bias[bcol + (p << 6) + col];
          const int row0 = (wr << 6) + (mi << 4) + ((lane >> 4) << 2);
#pragma unroll
          for (int rr = 0; rr < 4; ++rr)
            smf[(row0 + rr) << 6 | col] = acc[mi][nj][rr] + bb;
        }
    }
    __syncthreads();
#pragma unroll
    for (int it = 0; it < 8; ++it) {
      const int f = (it << 8) + tid;
      const int row = f >> 4, c4 = f & 15;
      float4 v = *(const float4*)(smf + (row << 6) + (c4 << 2));
      *(float4*)(dF + (size_t)(brow + row) * N + bcol + (p << 6) + (c4 << 2)) = v;
    }
  }
}

extern "C" void kernel_launch(void* const* d_in, const int* in_sizes, int n_in,
                              void* d_out, int out_size, void* d_ws, size_t ws_size,
                              hipStream_t stream) {
  const float* q  = (const float*)d_in[0];
  const float* Wq = (const float*)d_in[3];
  const float* bq = (const float*)d_in[4];
  const float* Wk = (const float*)d_in[5];
  const float* bk = (const float*)d_in[6];
  const float* Wv = (const float*)d_in[7];
  const float* bv = (const float*)d_in[8];
  const float* Wo = (const float*)d_in[9];
  const float* bo = (const float*)d_in[10];

  const int C = EMBED;
  const int M = in_sizes[0] / C;                 // 32768
  const size_t xsz = (size_t)M * C;
  const size_t wsz = (size_t)C * C;

  u16* Xb = (u16*)d_out;                         // scratch (overwritten by Wo GEMM)
  u16* Ob = (u16*)d_ws;                          // attention output, bf16 [M][768]
  u16* Wp = Ob + xsz;                            // per-head QKV weights [2304][768]
  u16* Wob = Wp + 3 * wsz;
  float* biasp = (float*)(Wob + wsz);            // 2304 f32 permuted bias

  {
    int n4 = (int)(xsz >> 2);
    cvt_f32_bf16<<<(n4 + 255) / 256, 256, 0, stream>>>(q, Xb, n4);
    const int nitems = 2304 * 192 + 768 * 192;   // QKV-perm + Wo, one launch
    cvt_weights<<<(nitems + 255) / 256, 256, 0, stream>>>(
        Wq, Wk, Wv, bq, bk, bv, Wo, Wp, biasp, Wob);
  }

  // Fused QKV projection + attention: 3072 blocks (rowblock-grouped per XCD)
  qkva<<<(M / 128) * HEADS, 512, 0, stream>>>(Xb, Wp, biasp, Ob);

  // Output projection: 1536 blocks (rowpanel-grouped per XCD, 4 blocks/CU)
  gemm128<<<(M / 128) * (C / 128), 256, 0, stream>>>(Ob, Wob, bo, (float*)d_out, C);
}